// Round 13
// baseline (16281.931 us; speedup 1.0000x reference)
//
#include <hip/hip_runtime.h>

#define B_   64
#define S_   512
#define EMB_ 512
#define HID_ 1024
#define NBLK_ 256

typedef float    f32x4 __attribute__((ext_vector_type(4)));
typedef unsigned u32x4 __attribute__((ext_vector_type(4)));

// Coherent (HBM/IC-side) access: sc0 sc1 bypasses L1+L2 -> no cache-wide
// fences needed for cross-XCD exchange. Proven R5/R8/R10/R11.
// RULES learned: (R9) inline-asm loads get NO compiler-inserted s_waitcnt —
// every consumer needs an explicit vmcnt wait + sched_barrier(0).
// (R12) NO runtime-indexed ext_vector arrays — they spill to scratch, and
// scratch buffer-ops count against vmcnt, silently breaking counted ladders.
__device__ __forceinline__ f32x4 ld_coh4(const float* p) {
    f32x4 d;
    asm volatile("global_load_dwordx4 %0, %1, off sc0 sc1" : "=v"(d) : "v"(p));
    return d;
}
__device__ __forceinline__ u32x4 ld_coh4u_wait(const unsigned* p) {
    u32x4 d;
    asm volatile("global_load_dwordx4 %0, %1, off sc0 sc1\n\t"
                 "s_waitcnt vmcnt(0)"
                 : "=v"(d) : "v"(p) : "memory");
    return d;
}
__device__ __forceinline__ void st_coh4(float* p, f32x4 v) {
    asm volatile("global_store_dwordx4 %0, %1, off sc0 sc1" :: "v"(p), "v"(v) : "memory");
}
__device__ __forceinline__ void st_coh1u(unsigned* p, unsigned v) {
    asm volatile("global_store_dword %0, %1, off sc0 sc1" :: "v"(p), "v"(v) : "memory");
}

// Flag barrier (proven R10/R11): arrival = one plain flag store per block;
// wait = wave0 lanes poll 4 flags each via dwordx4 with embedded vmcnt.
__device__ __forceinline__ void flag_barrier(unsigned* flags, int bk, int tid) {
    asm volatile("s_waitcnt vmcnt(0)" ::: "memory");  // own stores done
    __syncthreads();                                  // all waves drained
    if (tid == 0) st_coh1u(flags + bk, 1u);
    if (tid < 64) {
        const unsigned* fp = flags + tid * 4;
        for (;;) {
            u32x4 v = ld_coh4u_wait(fp);
            if (v[0] && v[1] && v[2] && v[3]) break;
            __builtin_amdgcn_s_sleep(1);
        }
    }
    __syncthreads();
}

// ---------------------------------------------------------------------------
// Kernel A: X1[t][b][n] = emb[x[b][t]][:] @ Wi1[:,n] + b1[n]  (fp32; chaotic
// recurrence -> no reduced precision anywhere feeding it, R6)
// ---------------------------------------------------------------------------
__global__ __launch_bounds__(256) void embed_gemm(
    const int* __restrict__ x, const float* __restrict__ emb,
    const float* __restrict__ Wi1, const float* __restrict__ b1,
    float* __restrict__ X1)
{
    __shared__ int   tok[128];
    __shared__ float aT[32][132];
    __shared__ float bl[32][68];

    const int tid = threadIdx.x;
    const int m0  = blockIdx.y * 128;
    const int n0  = blockIdx.x * 64;

    if (tid < 128) {
        int m = m0 + tid;
        tok[tid] = x[(m & 63) * S_ + (m >> 6)];
    }
    __syncthreads();

    const int tx = tid & 15;
    const int ty = tid >> 4;

    float acc[8][4];
#pragma unroll
    for (int r = 0; r < 8; ++r)
#pragma unroll
        for (int c = 0; c < 4; ++c) acc[r][c] = 0.f;

    for (int kt = 0; kt < EMB_; kt += 32) {
#pragma unroll
        for (int j = 0; j < 4; ++j) {
            int idx = tid + j * 256;
            int r   = idx >> 3;
            int k4  = (idx & 7) * 4;
            float4 v = *(const float4*)(emb + (size_t)tok[r] * EMB_ + kt + k4);
            aT[k4 + 0][r] = v.x; aT[k4 + 1][r] = v.y;
            aT[k4 + 2][r] = v.z; aT[k4 + 3][r] = v.w;
        }
#pragma unroll
        for (int j = 0; j < 2; ++j) {
            int idx = tid + j * 256;
            int k   = idx >> 4;
            int c4  = (idx & 15) * 4;
            *(float4*)&bl[k][c4] =
                *(const float4*)(Wi1 + (size_t)(kt + k) * HID_ + n0 + c4);
        }
        __syncthreads();

#pragma unroll 4
        for (int k = 0; k < 32; ++k) {
            float4 a0 = *(const float4*)&aT[k][ty * 8];
            float4 a1 = *(const float4*)&aT[k][ty * 8 + 4];
            float4 bv = *(const float4*)&bl[k][tx * 4];
            float ar[8] = {a0.x, a0.y, a0.z, a0.w, a1.x, a1.y, a1.z, a1.w};
            float bc[4] = {bv.x, bv.y, bv.z, bv.w};
#pragma unroll
            for (int r = 0; r < 8; ++r)
#pragma unroll
                for (int c = 0; c < 4; ++c) acc[r][c] += ar[r] * bc[c];
        }
        __syncthreads();
    }

    float4 bias = *(const float4*)(b1 + n0 + tx * 4);
#pragma unroll
    for (int r = 0; r < 8; ++r) {
        int m = m0 + ty * 8 + r;
        float4 o;
        o.x = acc[r][0] + bias.x; o.y = acc[r][1] + bias.y;
        o.z = acc[r][2] + bias.z; o.w = acc[r][3] + bias.w;
        *(float4*)(X1 + (size_t)m * HID_ + n0 + tx * 4) = o;
    }
}

// shfl_xor of a whole f32x4 (per component)
__device__ __forceinline__ f32x4 shfl_xor4(f32x4 v, int m) {
    f32x4 r;
#pragma unroll
    for (int e = 0; e < 4; ++e) r[e] = __shfl_xor(v[e], m, 64);
    return r;
}

// ---------------------------------------------------------------------------
// Kernel B: persistent split-k scan (R11 exchange/barriers; R12 phase-A
// structure with the reduce-scatter fix). Thread (row,kq) loads its own
// 32-k slice of h1/h2 directly (no LDS staging), FMAs under a vmcnt ladder,
// then a 2-round reduce-scatter over the 4 kq lanes leaves each lane holding
// exactly its own 8 output cols (constant indices only — no scratch).
// ---------------------------------------------------------------------------
__global__ __launch_bounds__(256, 1) void rnn_scan(
    const float* __restrict__ X1, const float* __restrict__ Wh1,
    const float* __restrict__ Wi2, const float* __restrict__ Wh2,
    const float* __restrict__ b2, float* __restrict__ hb,
    float* __restrict__ p1, float* __restrict__ p2,
    unsigned int* __restrict__ flagsA, unsigned int* __restrict__ flagsB)
{
    __shared__ float w1s[128 * 32];   // Wh1 slice, col-swizzled per k-quarter
    __shared__ float w2s[128 * 32];   // Wi2 slice
    __shared__ float w3s[128 * 32];   // Wh2 slice

    const int tid = threadIdx.x;
    const int bk  = blockIdx.x;
    const int kg  = bk >> 5;          // 0..7   k-group (128 k)
    const int cg  = bk & 31;          // 0..31  col-group (32 cols)
    const int k0  = kg * 128;
    const int cs0 = cg * 32;

    // Weight staging with kq-swizzle: value (k, c4) stored at
    // [k*32 + (c4 ^ ((k>>5 & 3)<<3))] so the 4 kq-lanes (k differing by 32)
    // read 4 distinct bank-sets -> conflict-free ds_read_b128.
    for (int idx = tid; idx < 1024; idx += 256) {
        int k  = idx >> 3, c4 = (idx & 7) * 4;
        int sc = c4 ^ (((k >> 5) & 3) << 3);
        *(f32x4*)&w1s[k * 32 + sc] = *(const f32x4*)(Wh1 + (size_t)(k0 + k) * HID_ + cs0 + c4);
        *(f32x4*)&w2s[k * 32 + sc] = *(const f32x4*)(Wi2 + (size_t)(k0 + k) * HID_ + cs0 + c4);
        *(f32x4*)&w3s[k * 32 + sc] = *(const f32x4*)(Wh2 + (size_t)(k0 + k) * HID_ + cs0 + c4);
    }

    const int row = tid >> 2;         // 0..63 batch row
    const int kq  = tid & 3;          // 0..3  k-quarter within the 128-k slice
    const int kqs = kq << 3;          // col swizzle term for this thread's k's
    const int kb0 = kq & 1;           // lane bit 0
    const int kb1 = (kq >> 1) & 1;    // lane bit 1

    const f32x4 b2v = *(const f32x4*)(b2 + bk * 4);

    float* h1buf[2] = { hb, hb + 65536 };
    float* h2buf[2] = { hb + 131072, hb + 196608 };

    __syncthreads();

    for (int i = 0; i <= S_; ++i) {
        const float* h1src = h1buf[(i + 1) & 1] + row * HID_ + k0 + kq * 32;
        const float* h2src = h2buf[i & 1]       + row * HID_ + k0 + kq * 32;

        // ---- issue all 16 h loads (interleaved h1/h2 per chunk) ----
        f32x4 va[8], vb[8];
#pragma unroll
        for (int c = 0; c < 8; ++c) {
            va[c] = ld_coh4(h1src + c * 4);
            vb[c] = ld_coh4(h2src + c * 4);
        }

        f32x4 a1[8], a2[8];
#pragma unroll
        for (int cc = 0; cc < 8; ++cc) { a1[cc] = (f32x4){0,0,0,0}; a2[cc] = (f32x4){0,0,0,0}; }

        // ---- vmcnt ladder: wait chunk c's pair, FMA against weights ----
#pragma unroll
        for (int c = 0; c < 8; ++c) {
            asm volatile("s_waitcnt vmcnt(%0)" :: "i"(14 - 2 * c) : "memory");
            __builtin_amdgcn_sched_barrier(0);
#pragma unroll
            for (int j = 0; j < 4; ++j) {
                const int k = kq * 32 + c * 4 + j;
                const float hx = va[c][j];
                const float hy = vb[c][j];
                const float* w1r = &w1s[k * 32];
                const float* w2r = &w2s[k * 32];
                const float* w3r = &w3s[k * 32];
#pragma unroll
                for (int cc = 0; cc < 8; ++cc) {
                    const int sc = (cc * 4) ^ kqs;
                    f32x4 wv1 = *(const f32x4*)(w1r + sc);
                    f32x4 wv2 = *(const f32x4*)(w2r + sc);
                    f32x4 wv3 = *(const f32x4*)(w3r + sc);
                    a1[cc] += hx * wv1;
                    a2[cc] += hx * wv2 + hy * wv3;
                }
            }
        }

        // ---- reduce-scatter over the 4 kq lanes (constant indices only) ----
        // Round 1 (partner kq^1, split on group bit1): keep groups with
        // g1 == kb0, i.e. t=0..3 -> group (t>>1)*4 + kb0*2 + (t&1).
        f32x4 r1[4], r2[4];
#pragma unroll
        for (int t = 0; t < 4; ++t) {
            const int ik = (t >> 1) * 4 + (t & 1);   // group if kb0==0
            f32x4 keep1 = kb0 ? a1[ik + 2] : a1[ik];
            f32x4 send1 = kb0 ? a1[ik]     : a1[ik + 2];
            f32x4 keep2 = kb0 ? a2[ik + 2] : a2[ik];
            f32x4 send2 = kb0 ? a2[ik]     : a2[ik + 2];
            r1[t] = keep1 + shfl_xor4(send1, 1);
            r2[t] = keep2 + shfl_xor4(send2, 1);
        }
        // Round 2 (partner kq^2, split on group bit2): keep t with t>>1==kb1.
        f32x4 f1a, f1b, f2a, f2b;
        {
            f32x4 k1a = kb1 ? r1[2] : r1[0];
            f32x4 s1a = kb1 ? r1[0] : r1[2];
            f32x4 k1b = kb1 ? r1[3] : r1[1];
            f32x4 s1b = kb1 ? r1[1] : r1[3];
            f32x4 k2a = kb1 ? r2[2] : r2[0];
            f32x4 s2a = kb1 ? r2[0] : r2[2];
            f32x4 k2b = kb1 ? r2[3] : r2[1];
            f32x4 s2b = kb1 ? r2[1] : r2[3];
            f1a = k1a + shfl_xor4(s1a, 2);
            f1b = k1b + shfl_xor4(s1b, 2);
            f2a = k2a + shfl_xor4(s2a, 2);
            f2b = k2b + shfl_xor4(s2b, 2);
        }
        // f1a/f1b hold groups 2kq, 2kq+1 = global cols cs0+8kq .. +8.

        // ---- write partials: thread writes cols cs0+kq*8 (32B) ----
        {
            float* pp1 = p1 + ((size_t)kg * 64 + row) * HID_ + cs0 + kq * 8;
            float* pp2 = p2 + ((size_t)kg * 64 + row) * HID_ + cs0 + kq * 8;
            st_coh4(pp1,     f1a);
            st_coh4(pp1 + 4, f1b);
            st_coh4(pp2,     f2a);
            st_coh4(pp2 + 4, f2b);
        }

        // ---- barrier A ----
        flag_barrier(flagsA + (size_t)i * 256, bk, tid);

        // ---- phase B: thread (row,kq) sums g8 = {2kq, 2kq+1}, shfl over kq ----
        {
            const float* q1 = p1 + ((size_t)(2 * kq) * 64 + row) * HID_ + bk * 4;
            const float* q2 = p2 + ((size_t)(2 * kq) * 64 + row) * HID_ + bk * 4;
            f32x4 pa = ld_coh4(q1);
            f32x4 pb = ld_coh4(q1 + (size_t)64 * HID_);
            f32x4 pc = ld_coh4(q2);
            f32x4 pd = ld_coh4(q2 + (size_t)64 * HID_);

            f32x4 xv = (f32x4){0,0,0,0};
            if (i < S_)   // plain cached load (X1 already includes b1)
                xv = *(const f32x4*)(X1 + ((size_t)i * B_ + row) * HID_ + bk * 4);

            asm volatile("s_waitcnt vmcnt(0)" ::: "memory");
            __builtin_amdgcn_sched_barrier(0);

            f32x4 s1 = pa + pb;
            f32x4 s2 = pc + pd;
#pragma unroll
            for (int m = 1; m <= 2; m <<= 1) {
                s1 += shfl_xor4(s1, m);
                s2 += shfl_xor4(s2, m);
            }

            if (kq == 0) {
                if (i < S_) {
                    f32x4 o;
                    o[0] = tanhf(xv[0] + s1[0]); o[1] = tanhf(xv[1] + s1[1]);
                    o[2] = tanhf(xv[2] + s1[2]); o[3] = tanhf(xv[3] + s1[3]);
                    st_coh4(h1buf[i & 1] + row * HID_ + bk * 4, o);
                }
                if (i >= 1) {
                    f32x4 o;
                    o[0] = tanhf(s2[0] + b2v[0]); o[1] = tanhf(s2[1] + b2v[1]);
                    o[2] = tanhf(s2[2] + b2v[2]); o[3] = tanhf(s2[3] + b2v[3]);
                    st_coh4(h2buf[(i + 1) & 1] + row * HID_ + bk * 4, o);
                }
            }
        }

        // ---- barrier B ----
        if (i < S_)
            flag_barrier(flagsB + (size_t)i * 256, bk, tid);
    }
    // h2(S-1) sits in h2buf[1] (= hb + 196608)
}

// ---------------------------------------------------------------------------
// out[b] = sigmoid(h2_last[b,:] @ Wd + bd)
// ---------------------------------------------------------------------------
__global__ void dense_sigmoid(const float* __restrict__ h2,
                              const float* __restrict__ Wd,
                              const float* __restrict__ bd,
                              float* __restrict__ out)
{
    int b = blockIdx.x, lane = threadIdx.x;
    float s = 0.f;
    for (int j = lane; j < HID_; j += 64) s += h2[b * HID_ + j] * Wd[j];
#pragma unroll
    for (int off = 32; off > 0; off >>= 1) s += __shfl_down(s, off, 64);
    if (lane == 0) out[b] = 1.f / (1.f + expf(-(s + bd[0])));
}

// ---------------------------------------------------------------------------
// ws layout (bytes):
//   hb     @ 0          1,048,576  (4 h buffers fp32)
//   flagsA @ 1,048,576    525,312  (513 steps x 256 u32)
//   flagsB @ 1,573,888    524,288  (512 steps x 256 u32)
//   p1     @ 2,098,176  2,097,152  (8 kg x 64 rows x 1024 cols fp32)
//   p2     @ 4,195,328  2,097,152
//   X1     @ 6,292,480  134,217,728 (S*B*HID fp32)
// memset zeroes hb+flagsA+flagsB = 2,098,176 B. (p1/p2/X1 written before read.)
// ---------------------------------------------------------------------------
extern "C" void kernel_launch(void* const* d_in, const int* in_sizes, int n_in,
                              void* d_out, int out_size, void* d_ws, size_t ws_size,
                              hipStream_t stream)
{
    const int*   x   = (const int*)  d_in[0];
    const float* emb = (const float*)d_in[1];
    const float* Wi1 = (const float*)d_in[2];
    const float* Wh1 = (const float*)d_in[3];
    const float* b1  = (const float*)d_in[4];
    const float* Wi2 = (const float*)d_in[5];
    const float* Wh2 = (const float*)d_in[6];
    const float* b2  = (const float*)d_in[7];
    const float* Wd  = (const float*)d_in[8];
    const float* bd  = (const float*)d_in[9];
    float* out = (float*)d_out;

    char* w = (char*)d_ws;
    float*        hb     = (float*)w;
    unsigned int* flagsA = (unsigned int*)(w + 1048576);
    unsigned int* flagsB = (unsigned int*)(w + 1573888);
    float*        p1     = (float*)(w + 2098176);
    float*        p2     = (float*)(w + 4195328);
    float*        X1     = (float*)(w + 6292480);

    hipMemsetAsync(w, 0, 2098176, stream);

    dim3 gA(HID_ / 64, (S_ * B_) / 128);
    embed_gemm<<<gA, dim3(256), 0, stream>>>(x, emb, Wi1, b1, X1);

    const float* X1c = X1;
    void* args[] = { (void*)&X1c, (void*)&Wh1, (void*)&Wi2, (void*)&Wh2,
                     (void*)&b2, (void*)&hb, (void*)&p1, (void*)&p2,
                     (void*)&flagsA, (void*)&flagsB };
    hipLaunchCooperativeKernel((const void*)rnn_scan, dim3(NBLK_), dim3(256),
                               args, 0, stream);

    dense_sigmoid<<<64, 64, 0, stream>>>(hb + 196608, Wd, bd, out);
}

// Round 14
// 16249.731 us; speedup vs baseline: 1.0020x; 1.0020x over previous
//
#include <hip/hip_runtime.h>

#define B_   64
#define S_   512
#define EMB_ 512
#define HID_ 1024
#define NBLK_ 256

typedef float    f32x4 __attribute__((ext_vector_type(4)));
typedef unsigned u32x4 __attribute__((ext_vector_type(4)));

// Coherent (HBM/IC-side) access: sc0 sc1 bypasses L1+L2 -> no cache-wide
// fences needed for cross-XCD exchange. Proven R5/R8/R10/R11.
// RULES learned: (R9) inline-asm loads get NO compiler-inserted s_waitcnt —
// every consumer needs an explicit vmcnt wait + sched_barrier(0).
// (R12) NO runtime-indexed ext_vector arrays — they spill to scratch, and
// scratch buffer-ops count against vmcnt, silently breaking counted ladders.
__device__ __forceinline__ f32x4 ld_coh4(const float* p) {
    f32x4 d;
    asm volatile("global_load_dwordx4 %0, %1, off sc0 sc1" : "=v"(d) : "v"(p));
    return d;
}
__device__ __forceinline__ u32x4 ld_coh4u_wait(const unsigned* p) {
    u32x4 d;
    asm volatile("global_load_dwordx4 %0, %1, off sc0 sc1\n\t"
                 "s_waitcnt vmcnt(0)"
                 : "=v"(d) : "v"(p) : "memory");
    return d;
}
__device__ __forceinline__ void st_coh4(float* p, f32x4 v) {
    asm volatile("global_store_dwordx4 %0, %1, off sc0 sc1" :: "v"(p), "v"(v) : "memory");
}
__device__ __forceinline__ void st_coh1u(unsigned* p, unsigned v) {
    asm volatile("global_store_dword %0, %1, off sc0 sc1" :: "v"(p), "v"(v) : "memory");
}

// Flag barrier (proven R10/R11): arrival = one plain flag store per block;
// wait = wave0 lanes poll 4 flags each via dwordx4 with embedded vmcnt.
__device__ __forceinline__ void flag_barrier(unsigned* flags, int bk, int tid) {
    asm volatile("s_waitcnt vmcnt(0)" ::: "memory");  // own stores done
    __syncthreads();                                  // all waves drained
    if (tid == 0) st_coh1u(flags + bk, 1u);
    if (tid < 64) {
        const unsigned* fp = flags + tid * 4;
        for (;;) {
            u32x4 v = ld_coh4u_wait(fp);
            if (v[0] && v[1] && v[2] && v[3]) break;
            __builtin_amdgcn_s_sleep(1);
        }
    }
    __syncthreads();
}

// ---------------------------------------------------------------------------
// Kernel A: X1[t][b][n] = emb[x[b][t]][:] @ Wi1[:,n] + b1[n]  (fp32; chaotic
// recurrence -> no reduced precision anywhere feeding it, R6)
// ---------------------------------------------------------------------------
__global__ __launch_bounds__(256) void embed_gemm(
    const int* __restrict__ x, const float* __restrict__ emb,
    const float* __restrict__ Wi1, const float* __restrict__ b1,
    float* __restrict__ X1)
{
    __shared__ int   tok[128];
    __shared__ float aT[32][132];
    __shared__ float bl[32][68];

    const int tid = threadIdx.x;
    const int m0  = blockIdx.y * 128;
    const int n0  = blockIdx.x * 64;

    if (tid < 128) {
        int m = m0 + tid;
        tok[tid] = x[(m & 63) * S_ + (m >> 6)];
    }
    __syncthreads();

    const int tx = tid & 15;
    const int ty = tid >> 4;

    float acc[8][4];
#pragma unroll
    for (int r = 0; r < 8; ++r)
#pragma unroll
        for (int c = 0; c < 4; ++c) acc[r][c] = 0.f;

    for (int kt = 0; kt < EMB_; kt += 32) {
#pragma unroll
        for (int j = 0; j < 4; ++j) {
            int idx = tid + j * 256;
            int r   = idx >> 3;
            int k4  = (idx & 7) * 4;
            float4 v = *(const float4*)(emb + (size_t)tok[r] * EMB_ + kt + k4);
            aT[k4 + 0][r] = v.x; aT[k4 + 1][r] = v.y;
            aT[k4 + 2][r] = v.z; aT[k4 + 3][r] = v.w;
        }
#pragma unroll
        for (int j = 0; j < 2; ++j) {
            int idx = tid + j * 256;
            int k   = idx >> 4;
            int c4  = (idx & 15) * 4;
            *(float4*)&bl[k][c4] =
                *(const float4*)(Wi1 + (size_t)(kt + k) * HID_ + n0 + c4);
        }
        __syncthreads();

#pragma unroll 4
        for (int k = 0; k < 32; ++k) {
            float4 a0 = *(const float4*)&aT[k][ty * 8];
            float4 a1 = *(const float4*)&aT[k][ty * 8 + 4];
            float4 bv = *(const float4*)&bl[k][tx * 4];
            float ar[8] = {a0.x, a0.y, a0.z, a0.w, a1.x, a1.y, a1.z, a1.w};
            float bc[4] = {bv.x, bv.y, bv.z, bv.w};
#pragma unroll
            for (int r = 0; r < 8; ++r)
#pragma unroll
                for (int c = 0; c < 4; ++c) acc[r][c] += ar[r] * bc[c];
        }
        __syncthreads();
    }

    float4 bias = *(const float4*)(b1 + n0 + tx * 4);
#pragma unroll
    for (int r = 0; r < 8; ++r) {
        int m = m0 + ty * 8 + r;
        float4 o;
        o.x = acc[r][0] + bias.x; o.y = acc[r][1] + bias.y;
        o.z = acc[r][2] + bias.z; o.w = acc[r][3] + bias.w;
        *(float4*)(X1 + (size_t)m * HID_ + n0 + tx * 4) = o;
    }
}

// shfl_xor of a whole f32x4 (per component)
__device__ __forceinline__ f32x4 shfl_xor4(f32x4 v, int m) {
    f32x4 r;
#pragma unroll
    for (int e = 0; e < 4; ++e) r[e] = __shfl_xor(v[e], m, 64);
    return r;
}

// ---------------------------------------------------------------------------
// Kernel B: persistent split-k scan (R11 exchange/barriers; R12 phase-A
// structure with the reduce-scatter fix). Thread (row,kq) loads its own
// 32-k slice of h1/h2 directly (no LDS staging), FMAs under a vmcnt ladder,
// then a 2-round reduce-scatter over the 4 kq lanes leaves each lane holding
// exactly its own 8 output cols (constant indices only — no scratch).
// ---------------------------------------------------------------------------
__global__ __launch_bounds__(256, 1) void rnn_scan(
    const float* __restrict__ X1, const float* __restrict__ Wh1,
    const float* __restrict__ Wi2, const float* __restrict__ Wh2,
    const float* __restrict__ b2, float* __restrict__ hb,
    float* __restrict__ p1, float* __restrict__ p2,
    unsigned int* __restrict__ flagsA, unsigned int* __restrict__ flagsB)
{
    __shared__ float w1s[128 * 32];   // Wh1 slice, col-swizzled per k-quarter
    __shared__ float w2s[128 * 32];   // Wi2 slice
    __shared__ float w3s[128 * 32];   // Wh2 slice

    const int tid = threadIdx.x;
    const int bk  = blockIdx.x;
    const int kg  = bk >> 5;          // 0..7   k-group (128 k)
    const int cg  = bk & 31;          // 0..31  col-group (32 cols)
    const int k0  = kg * 128;
    const int cs0 = cg * 32;

    // Weight staging with kq-swizzle: value (k, c4) stored at
    // [k*32 + (c4 ^ ((k>>5 & 3)<<3))] so the 4 kq-lanes (k differing by 32)
    // read 4 distinct bank-sets -> conflict-free ds_read_b128.
    for (int idx = tid; idx < 1024; idx += 256) {
        int k  = idx >> 3, c4 = (idx & 7) * 4;
        int sc = c4 ^ (((k >> 5) & 3) << 3);
        *(f32x4*)&w1s[k * 32 + sc] = *(const f32x4*)(Wh1 + (size_t)(k0 + k) * HID_ + cs0 + c4);
        *(f32x4*)&w2s[k * 32 + sc] = *(const f32x4*)(Wi2 + (size_t)(k0 + k) * HID_ + cs0 + c4);
        *(f32x4*)&w3s[k * 32 + sc] = *(const f32x4*)(Wh2 + (size_t)(k0 + k) * HID_ + cs0 + c4);
    }

    const int row = tid >> 2;         // 0..63 batch row
    const int kq  = tid & 3;          // 0..3  k-quarter within the 128-k slice
    const int kqs = kq << 3;          // col swizzle term for this thread's k's
    const int kb0 = kq & 1;           // lane bit 0
    const int kb1 = (kq >> 1) & 1;    // lane bit 1

    const f32x4 b2v = *(const f32x4*)(b2 + bk * 4);

    float* h1buf[2] = { hb, hb + 65536 };
    float* h2buf[2] = { hb + 131072, hb + 196608 };

    __syncthreads();

    for (int i = 0; i <= S_; ++i) {
        const float* h1src = h1buf[(i + 1) & 1] + row * HID_ + k0 + kq * 32;
        const float* h2src = h2buf[i & 1]       + row * HID_ + k0 + kq * 32;

        // ---- issue all 16 h loads (interleaved h1/h2 per chunk) ----
        f32x4 va[8], vb[8];
#pragma unroll
        for (int c = 0; c < 8; ++c) {
            va[c] = ld_coh4(h1src + c * 4);
            vb[c] = ld_coh4(h2src + c * 4);
        }

        f32x4 a1[8], a2[8];
#pragma unroll
        for (int cc = 0; cc < 8; ++cc) { a1[cc] = (f32x4){0,0,0,0}; a2[cc] = (f32x4){0,0,0,0}; }

        // ---- vmcnt ladder: wait chunk c's pair, FMA against weights ----
#pragma unroll
        for (int c = 0; c < 8; ++c) {
            asm volatile("s_waitcnt vmcnt(%0)" :: "i"(14 - 2 * c) : "memory");
            __builtin_amdgcn_sched_barrier(0);
#pragma unroll
            for (int j = 0; j < 4; ++j) {
                const int k = kq * 32 + c * 4 + j;
                const float hx = va[c][j];
                const float hy = vb[c][j];
                const float* w1r = &w1s[k * 32];
                const float* w2r = &w2s[k * 32];
                const float* w3r = &w3s[k * 32];
#pragma unroll
                for (int cc = 0; cc < 8; ++cc) {
                    const int sc = (cc * 4) ^ kqs;
                    f32x4 wv1 = *(const f32x4*)(w1r + sc);
                    f32x4 wv2 = *(const f32x4*)(w2r + sc);
                    f32x4 wv3 = *(const f32x4*)(w3r + sc);
                    a1[cc] += hx * wv1;
                    a2[cc] += hx * wv2 + hy * wv3;
                }
            }
        }

        // ---- reduce-scatter over the 4 kq lanes (constant indices only) ----
        // Round 1 (partner kq^1, split on group bit1): keep groups with
        // g1 == kb0, i.e. t=0..3 -> group (t>>1)*4 + kb0*2 + (t&1).
        f32x4 r1[4], r2[4];
#pragma unroll
        for (int t = 0; t < 4; ++t) {
            const int ik = (t >> 1) * 4 + (t & 1);   // group if kb0==0
            f32x4 keep1 = kb0 ? a1[ik + 2] : a1[ik];
            f32x4 send1 = kb0 ? a1[ik]     : a1[ik + 2];
            f32x4 keep2 = kb0 ? a2[ik + 2] : a2[ik];
            f32x4 send2 = kb0 ? a2[ik]     : a2[ik + 2];
            r1[t] = keep1 + shfl_xor4(send1, 1);
            r2[t] = keep2 + shfl_xor4(send2, 1);
        }
        // Round 2 (partner kq^2, split on group bit2): keep t with t>>1==kb1.
        f32x4 f1a, f1b, f2a, f2b;
        {
            f32x4 k1a = kb1 ? r1[2] : r1[0];
            f32x4 s1a = kb1 ? r1[0] : r1[2];
            f32x4 k1b = kb1 ? r1[3] : r1[1];
            f32x4 s1b = kb1 ? r1[1] : r1[3];
            f32x4 k2a = kb1 ? r2[2] : r2[0];
            f32x4 s2a = kb1 ? r2[0] : r2[2];
            f32x4 k2b = kb1 ? r2[3] : r2[1];
            f32x4 s2b = kb1 ? r2[1] : r2[3];
            f1a = k1a + shfl_xor4(s1a, 2);
            f1b = k1b + shfl_xor4(s1b, 2);
            f2a = k2a + shfl_xor4(s2a, 2);
            f2b = k2b + shfl_xor4(s2b, 2);
        }
        // f1a/f1b hold groups 2kq, 2kq+1 = global cols cs0+8kq .. +8.

        // ---- write partials: thread writes cols cs0+kq*8 (32B) ----
        {
            float* pp1 = p1 + ((size_t)kg * 64 + row) * HID_ + cs0 + kq * 8;
            float* pp2 = p2 + ((size_t)kg * 64 + row) * HID_ + cs0 + kq * 8;
            st_coh4(pp1,     f1a);
            st_coh4(pp1 + 4, f1b);
            st_coh4(pp2,     f2a);
            st_coh4(pp2 + 4, f2b);
        }

        // ---- barrier A ----
        flag_barrier(flagsA + (size_t)i * 256, bk, tid);

        // ---- phase B: thread (row,kq) sums g8 = {2kq, 2kq+1}, shfl over kq ----
        {
            const float* q1 = p1 + ((size_t)(2 * kq) * 64 + row) * HID_ + bk * 4;
            const float* q2 = p2 + ((size_t)(2 * kq) * 64 + row) * HID_ + bk * 4;
            f32x4 pa = ld_coh4(q1);
            f32x4 pb = ld_coh4(q1 + (size_t)64 * HID_);
            f32x4 pc = ld_coh4(q2);
            f32x4 pd = ld_coh4(q2 + (size_t)64 * HID_);

            f32x4 xv = (f32x4){0,0,0,0};
            if (i < S_)   // plain cached load (X1 already includes b1)
                xv = *(const f32x4*)(X1 + ((size_t)i * B_ + row) * HID_ + bk * 4);

            asm volatile("s_waitcnt vmcnt(0)" ::: "memory");
            __builtin_amdgcn_sched_barrier(0);

            f32x4 s1 = pa + pb;
            f32x4 s2 = pc + pd;
#pragma unroll
            for (int m = 1; m <= 2; m <<= 1) {
                s1 += shfl_xor4(s1, m);
                s2 += shfl_xor4(s2, m);
            }

            if (kq == 0) {
                if (i < S_) {
                    f32x4 o;
                    o[0] = tanhf(xv[0] + s1[0]); o[1] = tanhf(xv[1] + s1[1]);
                    o[2] = tanhf(xv[2] + s1[2]); o[3] = tanhf(xv[3] + s1[3]);
                    st_coh4(h1buf[i & 1] + row * HID_ + bk * 4, o);
                }
                if (i >= 1) {
                    f32x4 o;
                    o[0] = tanhf(s2[0] + b2v[0]); o[1] = tanhf(s2[1] + b2v[1]);
                    o[2] = tanhf(s2[2] + b2v[2]); o[3] = tanhf(s2[3] + b2v[3]);
                    st_coh4(h2buf[(i + 1) & 1] + row * HID_ + bk * 4, o);
                }
            }
        }

        // ---- barrier B ----
        if (i < S_)
            flag_barrier(flagsB + (size_t)i * 256, bk, tid);
    }
    // h2(S-1) sits in h2buf[1] (= hb + 196608)
}

// ---------------------------------------------------------------------------
// out[b] = sigmoid(h2_last[b,:] @ Wd + bd)
// ---------------------------------------------------------------------------
__global__ void dense_sigmoid(const float* __restrict__ h2,
                              const float* __restrict__ Wd,
                              const float* __restrict__ bd,
                              float* __restrict__ out)
{
    int b = blockIdx.x, lane = threadIdx.x;
    float s = 0.f;
    for (int j = lane; j < HID_; j += 64) s += h2[b * HID_ + j] * Wd[j];
#pragma unroll
    for (int off = 32; off > 0; off >>= 1) s += __shfl_down(s, off, 64);
    if (lane == 0) out[b] = 1.f / (1.f + expf(-(s + bd[0])));
}

// ---------------------------------------------------------------------------
// ws layout (bytes):
//   hb     @ 0          1,048,576  (4 h buffers fp32)
//   flagsA @ 1,048,576    525,312  (513 steps x 256 u32)
//   flagsB @ 1,573,888    524,288  (512 steps x 256 u32)
//   p1     @ 2,098,176  2,097,152  (8 kg x 64 rows x 1024 cols fp32)
//   p2     @ 4,195,328  2,097,152
//   X1     @ 6,292,480  134,217,728 (S*B*HID fp32)
// memset zeroes hb+flagsA+flagsB = 2,098,176 B. (p1/p2/X1 written before read.)
// ---------------------------------------------------------------------------
extern "C" void kernel_launch(void* const* d_in, const int* in_sizes, int n_in,
                              void* d_out, int out_size, void* d_ws, size_t ws_size,
                              hipStream_t stream)
{
    const int*   x   = (const int*)  d_in[0];
    const float* emb = (const float*)d_in[1];
    const float* Wi1 = (const float*)d_in[2];
    const float* Wh1 = (const float*)d_in[3];
    const float* b1  = (const float*)d_in[4];
    const float* Wi2 = (const float*)d_in[5];
    const float* Wh2 = (const float*)d_in[6];
    const float* b2  = (const float*)d_in[7];
    const float* Wd  = (const float*)d_in[8];
    const float* bd  = (const float*)d_in[9];
    float* out = (float*)d_out;

    char* w = (char*)d_ws;
    float*        hb     = (float*)w;
    unsigned int* flagsA = (unsigned int*)(w + 1048576);
    unsigned int* flagsB = (unsigned int*)(w + 1573888);
    float*        p1     = (float*)(w + 2098176);
    float*        p2     = (float*)(w + 4195328);
    float*        X1     = (float*)(w + 6292480);

    hipMemsetAsync(w, 0, 2098176, stream);

    dim3 gA(HID_ / 64, (S_ * B_) / 128);
    embed_gemm<<<gA, dim3(256), 0, stream>>>(x, emb, Wi1, b1, X1);

    const float* X1c = X1;
    void* args[] = { (void*)&X1c, (void*)&Wh1, (void*)&Wi2, (void*)&Wh2,
                     (void*)&b2, (void*)&hb, (void*)&p1, (void*)&p2,
                     (void*)&flagsA, (void*)&flagsB };
    hipLaunchCooperativeKernel((const void*)rnn_scan, dim3(NBLK_), dim3(256),
                               args, 0, stream);

    dense_sigmoid<<<64, 64, 0, stream>>>(hb + 196608, Wd, bd, out);
}

// Round 15
// 14095.766 us; speedup vs baseline: 1.1551x; 1.1528x over previous
//
#include <hip/hip_runtime.h>

#define B_   64
#define S_   512
#define EMB_ 512
#define HID_ 1024
#define NBLK_ 256

typedef float f32x4 __attribute__((ext_vector_type(4)));

// Coherent (HBM/IC-side) access: sc0 sc1 bypasses L1+L2 -> no cache-wide
// fences needed for cross-XCD exchange. Proven R5/R8/R10/R11/R14.
// RULES learned: (R9) inline-asm loads get NO compiler-inserted s_waitcnt —
// every consumer needs an explicit vmcnt wait + sched_barrier(0).
// (R12) NO runtime-indexed ext_vector arrays — they spill to scratch, and
// scratch buffer-ops count against vmcnt, silently breaking counted ladders.
__device__ __forceinline__ f32x4 ld_coh4(const float* p) {
    f32x4 d;
    asm volatile("global_load_dwordx4 %0, %1, off sc0 sc1" : "=v"(d) : "v"(p));
    return d;
}
__device__ __forceinline__ void st_coh4(float* p, f32x4 v) {
    asm volatile("global_store_dwordx4 %0, %1, off sc0 sc1" :: "v"(p), "v"(v) : "memory");
}
__device__ __forceinline__ void st_coh1u(unsigned* p, unsigned v) {
    asm volatile("global_store_dword %0, %1, off sc0 sc1" :: "v"(p), "v"(v) : "memory");
}
// Single-flag poll load with embedded vmcnt wait.
__device__ __forceinline__ unsigned ld_cohu_wait(const unsigned* p) {
    unsigned d;
    asm volatile("global_load_dword %0, %1, off sc0 sc1\n\t"
                 "s_waitcnt vmcnt(0)"
                 : "=v"(d) : "v"(p) : "memory");
    return d;
}

// ---------------------------------------------------------------------------
// Kernel A: X1[t][b][n] = emb[x[b][t]][:] @ Wi1[:,n] + b1[n]  (fp32; chaotic
// recurrence -> no reduced precision anywhere feeding it, R6)
// ---------------------------------------------------------------------------
__global__ __launch_bounds__(256) void embed_gemm(
    const int* __restrict__ x, const float* __restrict__ emb,
    const float* __restrict__ Wi1, const float* __restrict__ b1,
    float* __restrict__ X1)
{
    __shared__ int   tok[128];
    __shared__ float aT[32][132];
    __shared__ float bl[32][68];

    const int tid = threadIdx.x;
    const int m0  = blockIdx.y * 128;
    const int n0  = blockIdx.x * 64;

    if (tid < 128) {
        int m = m0 + tid;
        tok[tid] = x[(m & 63) * S_ + (m >> 6)];
    }
    __syncthreads();

    const int tx = tid & 15;
    const int ty = tid >> 4;

    float acc[8][4];
#pragma unroll
    for (int r = 0; r < 8; ++r)
#pragma unroll
        for (int c = 0; c < 4; ++c) acc[r][c] = 0.f;

    for (int kt = 0; kt < EMB_; kt += 32) {
#pragma unroll
        for (int j = 0; j < 4; ++j) {
            int idx = tid + j * 256;
            int r   = idx >> 3;
            int k4  = (idx & 7) * 4;
            float4 v = *(const float4*)(emb + (size_t)tok[r] * EMB_ + kt + k4);
            aT[k4 + 0][r] = v.x; aT[k4 + 1][r] = v.y;
            aT[k4 + 2][r] = v.z; aT[k4 + 3][r] = v.w;
        }
#pragma unroll
        for (int j = 0; j < 2; ++j) {
            int idx = tid + j * 256;
            int k   = idx >> 4;
            int c4  = (idx & 15) * 4;
            *(float4*)&bl[k][c4] =
                *(const float4*)(Wi1 + (size_t)(kt + k) * HID_ + n0 + c4);
        }
        __syncthreads();

#pragma unroll 4
        for (int k = 0; k < 32; ++k) {
            float4 a0 = *(const float4*)&aT[k][ty * 8];
            float4 a1 = *(const float4*)&aT[k][ty * 8 + 4];
            float4 bv = *(const float4*)&bl[k][tx * 4];
            float ar[8] = {a0.x, a0.y, a0.z, a0.w, a1.x, a1.y, a1.z, a1.w};
            float bc[4] = {bv.x, bv.y, bv.z, bv.w};
#pragma unroll
            for (int r = 0; r < 8; ++r)
#pragma unroll
                for (int c = 0; c < 4; ++c) acc[r][c] += ar[r] * bc[c];
        }
        __syncthreads();
    }

    float4 bias = *(const float4*)(b1 + n0 + tx * 4);
#pragma unroll
    for (int r = 0; r < 8; ++r) {
        int m = m0 + ty * 8 + r;
        float4 o;
        o.x = acc[r][0] + bias.x; o.y = acc[r][1] + bias.y;
        o.z = acc[r][2] + bias.z; o.w = acc[r][3] + bias.w;
        *(float4*)(X1 + (size_t)m * HID_ + n0 + tx * 4) = o;
    }
}

// shfl_xor of a whole f32x4 (per component)
__device__ __forceinline__ f32x4 shfl_xor4(f32x4 v, int m) {
    f32x4 r;
#pragma unroll
    for (int e = 0; e < 4; ++e) r[e] = __shfl_xor(v[e], m, 64);
    return r;
}

// ---------------------------------------------------------------------------
// Kernel B: persistent split-k scan with SPARSE producer waits (no global
// barriers). Key property of the decomposition: the 32 blocks reading h
// k-slice kg == the 32 blocks writing h cols [128kg,128kg+128).
//   W1 (pre phase A of step i): wait flagsB[i-1] of [32kg..+32) (h RAW)
//      and [8cg..+8) (my p-slice's step-(i-1) readers -> p WAR).
//   W2 (pre phase B): wait flagsA[i][cgp*8..+8] (my 8 kg-producers; flagA
//      laid out [i][cg][kg] for contiguity).
//   WAR on the 2-deep h rotation is transitively covered: a step-(i+1)
//   phase-B writer passed W2(i+1) <= its 8 producers' W1(i+1) <= flagsB[i]
//   of EVERY kg-set => all step-i readers are done. (Checked incl. startup.)
// ---------------------------------------------------------------------------
__global__ __launch_bounds__(256, 1) void rnn_scan(
    const float* __restrict__ X1, const float* __restrict__ Wh1,
    const float* __restrict__ Wi2, const float* __restrict__ Wh2,
    const float* __restrict__ b2, float* __restrict__ hb,
    float* __restrict__ p1, float* __restrict__ p2,
    unsigned int* __restrict__ flagsA, unsigned int* __restrict__ flagsB)
{
    __shared__ float w1s[128 * 32];   // Wh1 slice, col-swizzled per k-quarter
    __shared__ float w2s[128 * 32];   // Wi2 slice
    __shared__ float w3s[128 * 32];   // Wh2 slice

    const int tid = threadIdx.x;
    const int bk  = blockIdx.x;
    const int kg  = bk >> 5;          // 0..7   k-group (128 k)
    const int cg  = bk & 31;          // 0..31  col-group (32 cols)
    const int cgp = bk >> 3;          // col-slice containing my output cols
    const int k0  = kg * 128;
    const int cs0 = cg * 32;

    // Weight staging with kq-swizzle: value (k, c4) stored at
    // [k*32 + (c4 ^ ((k>>5 & 3)<<3))] -> the 4 kq-lanes read 4 distinct
    // bank-sets -> conflict-free ds_read_b128.
    for (int idx = tid; idx < 1024; idx += 256) {
        int k  = idx >> 3, c4 = (idx & 7) * 4;
        int sc = c4 ^ (((k >> 5) & 3) << 3);
        *(f32x4*)&w1s[k * 32 + sc] = *(const f32x4*)(Wh1 + (size_t)(k0 + k) * HID_ + cs0 + c4);
        *(f32x4*)&w2s[k * 32 + sc] = *(const f32x4*)(Wi2 + (size_t)(k0 + k) * HID_ + cs0 + c4);
        *(f32x4*)&w3s[k * 32 + sc] = *(const f32x4*)(Wh2 + (size_t)(k0 + k) * HID_ + cs0 + c4);
    }

    const int row = tid >> 2;         // 0..63 batch row
    const int kq  = tid & 3;          // 0..3  k-quarter within the 128-k slice
    const int kqs = kq << 3;          // col swizzle term for this thread's k's
    const int kb0 = kq & 1;           // lane bit 0
    const int kb1 = (kq >> 1) & 1;    // lane bit 1

    const f32x4 b2v = *(const f32x4*)(b2 + bk * 4);

    float* h1buf[2] = { hb, hb + 65536 };
    float* h2buf[2] = { hb + 131072, hb + 196608 };

    __syncthreads();

    for (int i = 0; i <= S_; ++i) {
        // ---- W1: sparse wait on step-(i-1) phase-B producers ----
        if (i >= 1) {
            const unsigned* fb = flagsB + (size_t)(i - 1) * 256;
            if (tid < 40) {
                int idx = (tid < 32) ? (kg * 32 + tid) : (cg * 8 + (tid - 32));
                while (ld_cohu_wait(fb + idx) == 0) __builtin_amdgcn_s_sleep(1);
            }
            __syncthreads();
        }

        const float* h1src = h1buf[(i + 1) & 1] + row * HID_ + k0 + kq * 32;
        const float* h2src = h2buf[i & 1]       + row * HID_ + k0 + kq * 32;

        // ---- issue all 16 h loads (interleaved h1/h2 per chunk) ----
        f32x4 va[8], vb[8];
#pragma unroll
        for (int c = 0; c < 8; ++c) {
            va[c] = ld_coh4(h1src + c * 4);
            vb[c] = ld_coh4(h2src + c * 4);
        }

        f32x4 a1[8], a2[8];
#pragma unroll
        for (int cc = 0; cc < 8; ++cc) { a1[cc] = (f32x4){0,0,0,0}; a2[cc] = (f32x4){0,0,0,0}; }

        // ---- vmcnt ladder: wait chunk c's pair, FMA against weights ----
#pragma unroll
        for (int c = 0; c < 8; ++c) {
            asm volatile("s_waitcnt vmcnt(%0)" :: "i"(14 - 2 * c) : "memory");
            __builtin_amdgcn_sched_barrier(0);
#pragma unroll
            for (int j = 0; j < 4; ++j) {
                const int k = kq * 32 + c * 4 + j;
                const float hx = va[c][j];
                const float hy = vb[c][j];
                const float* w1r = &w1s[k * 32];
                const float* w2r = &w2s[k * 32];
                const float* w3r = &w3s[k * 32];
#pragma unroll
                for (int cc = 0; cc < 8; ++cc) {
                    const int sc = (cc * 4) ^ kqs;
                    f32x4 wv1 = *(const f32x4*)(w1r + sc);
                    f32x4 wv2 = *(const f32x4*)(w2r + sc);
                    f32x4 wv3 = *(const f32x4*)(w3r + sc);
                    a1[cc] += hx * wv1;
                    a2[cc] += hx * wv2 + hy * wv3;
                }
            }
        }

        // ---- reduce-scatter over the 4 kq lanes (constant indices only) ----
        f32x4 r1[4], r2[4];
#pragma unroll
        for (int t = 0; t < 4; ++t) {
            const int ik = (t >> 1) * 4 + (t & 1);   // group if kb0==0
            f32x4 keep1 = kb0 ? a1[ik + 2] : a1[ik];
            f32x4 send1 = kb0 ? a1[ik]     : a1[ik + 2];
            f32x4 keep2 = kb0 ? a2[ik + 2] : a2[ik];
            f32x4 send2 = kb0 ? a2[ik]     : a2[ik + 2];
            r1[t] = keep1 + shfl_xor4(send1, 1);
            r2[t] = keep2 + shfl_xor4(send2, 1);
        }
        f32x4 f1a, f1b, f2a, f2b;
        {
            f32x4 k1a = kb1 ? r1[2] : r1[0];
            f32x4 s1a = kb1 ? r1[0] : r1[2];
            f32x4 k1b = kb1 ? r1[3] : r1[1];
            f32x4 s1b = kb1 ? r1[1] : r1[3];
            f32x4 k2a = kb1 ? r2[2] : r2[0];
            f32x4 s2a = kb1 ? r2[0] : r2[2];
            f32x4 k2b = kb1 ? r2[3] : r2[1];
            f32x4 s2b = kb1 ? r2[1] : r2[3];
            f1a = k1a + shfl_xor4(s1a, 2);
            f1b = k1b + shfl_xor4(s1b, 2);
            f2a = k2a + shfl_xor4(s2a, 2);
            f2b = k2b + shfl_xor4(s2b, 2);
        }
        // f1a/f1b hold groups 2kq, 2kq+1 = global cols cs0+8kq .. +8.

        // ---- write partials: thread writes cols cs0+kq*8 (32B) ----
        {
            float* pp1 = p1 + ((size_t)kg * 64 + row) * HID_ + cs0 + kq * 8;
            float* pp2 = p2 + ((size_t)kg * 64 + row) * HID_ + cs0 + kq * 8;
            st_coh4(pp1,     f1a);
            st_coh4(pp1 + 4, f1b);
            st_coh4(pp2,     f2a);
            st_coh4(pp2 + 4, f2b);
        }

        // ---- signal p ready (flagA[i][cg*8+kg]) ----
        asm volatile("s_waitcnt vmcnt(0)" ::: "memory");
        __syncthreads();
        if (tid == 0) st_coh1u(flagsA + (size_t)i * 256 + cg * 8 + kg, 1u);

        // ---- W2: wait my 8 kg-producers' p for cols [4bk,4bk+4) ----
        {
            const unsigned* fa = flagsA + (size_t)i * 256 + cgp * 8;
            if (tid < 8) {
                while (ld_cohu_wait(fa + tid) == 0) __builtin_amdgcn_s_sleep(1);
            }
            __syncthreads();
        }

        // ---- phase B: thread (row,kq) sums g8 = {2kq, 2kq+1}, shfl over kq ----
        {
            const float* q1 = p1 + ((size_t)(2 * kq) * 64 + row) * HID_ + bk * 4;
            const float* q2 = p2 + ((size_t)(2 * kq) * 64 + row) * HID_ + bk * 4;
            f32x4 pa = ld_coh4(q1);
            f32x4 pb = ld_coh4(q1 + (size_t)64 * HID_);
            f32x4 pc = ld_coh4(q2);
            f32x4 pd = ld_coh4(q2 + (size_t)64 * HID_);

            f32x4 xv = (f32x4){0,0,0,0};
            if (i < S_)   // plain cached load (X1 already includes b1)
                xv = *(const f32x4*)(X1 + ((size_t)i * B_ + row) * HID_ + bk * 4);

            asm volatile("s_waitcnt vmcnt(0)" ::: "memory");
            __builtin_amdgcn_sched_barrier(0);

            f32x4 s1 = pa + pb;
            f32x4 s2 = pc + pd;
#pragma unroll
            for (int m = 1; m <= 2; m <<= 1) {
                s1 += shfl_xor4(s1, m);
                s2 += shfl_xor4(s2, m);
            }

            if (kq == 0) {
                if (i < S_) {
                    f32x4 o;
                    o[0] = tanhf(xv[0] + s1[0]); o[1] = tanhf(xv[1] + s1[1]);
                    o[2] = tanhf(xv[2] + s1[2]); o[3] = tanhf(xv[3] + s1[3]);
                    st_coh4(h1buf[i & 1] + row * HID_ + bk * 4, o);
                }
                if (i >= 1) {
                    f32x4 o;
                    o[0] = tanhf(s2[0] + b2v[0]); o[1] = tanhf(s2[1] + b2v[1]);
                    o[2] = tanhf(s2[2] + b2v[2]); o[3] = tanhf(s2[3] + b2v[3]);
                    st_coh4(h2buf[(i + 1) & 1] + row * HID_ + bk * 4, o);
                }
            }
        }

        // ---- signal h ready (flagB[i][bk]); no global poll ----
        if (i < S_) {
            asm volatile("s_waitcnt vmcnt(0)" ::: "memory");
            __syncthreads();
            if (tid == 0) st_coh1u(flagsB + (size_t)i * 256 + bk, 1u);
        }
    }
    // h2(S-1) sits in h2buf[1] (= hb + 196608)
}

// ---------------------------------------------------------------------------
// out[b] = sigmoid(h2_last[b,:] @ Wd + bd)
// ---------------------------------------------------------------------------
__global__ void dense_sigmoid(const float* __restrict__ h2,
                              const float* __restrict__ Wd,
                              const float* __restrict__ bd,
                              float* __restrict__ out)
{
    int b = blockIdx.x, lane = threadIdx.x;
    float s = 0.f;
    for (int j = lane; j < HID_; j += 64) s += h2[b * HID_ + j] * Wd[j];
#pragma unroll
    for (int off = 32; off > 0; off >>= 1) s += __shfl_down(s, off, 64);
    if (lane == 0) out[b] = 1.f / (1.f + expf(-(s + bd[0])));
}

// ---------------------------------------------------------------------------
// ws layout (bytes) — identical to R14:
//   hb     @ 0          1,048,576  (4 h buffers fp32)
//   flagsA @ 1,048,576    525,312  (513 steps x 256 u32, [i][cg*8+kg])
//   flagsB @ 1,573,888    524,288  (512 steps x 256 u32, [i][bk])
//   p1     @ 2,098,176  2,097,152  (8 kg x 64 rows x 1024 cols fp32)
//   p2     @ 4,195,328  2,097,152
//   X1     @ 6,292,480  134,217,728 (S*B*HID fp32)
// memset zeroes hb+flagsA+flagsB = 2,098,176 B. (p1/p2/X1 written before read.)
// ---------------------------------------------------------------------------
extern "C" void kernel_launch(void* const* d_in, const int* in_sizes, int n_in,
                              void* d_out, int out_size, void* d_ws, size_t ws_size,
                              hipStream_t stream)
{
    const int*   x   = (const int*)  d_in[0];
    const float* emb = (const float*)d_in[1];
    const float* Wi1 = (const float*)d_in[2];
    const float* Wh1 = (const float*)d_in[3];
    const float* b1  = (const float*)d_in[4];
    const float* Wi2 = (const float*)d_in[5];
    const float* Wh2 = (const float*)d_in[6];
    const float* b2  = (const float*)d_in[7];
    const float* Wd  = (const float*)d_in[8];
    const float* bd  = (const float*)d_in[9];
    float* out = (float*)d_out;

    char* w = (char*)d_ws;
    float*        hb     = (float*)w;
    unsigned int* flagsA = (unsigned int*)(w + 1048576);
    unsigned int* flagsB = (unsigned int*)(w + 1573888);
    float*        p1     = (float*)(w + 2098176);
    float*        p2     = (float*)(w + 4195328);
    float*        X1     = (float*)(w + 6292480);

    hipMemsetAsync(w, 0, 2098176, stream);

    dim3 gA(HID_ / 64, (S_ * B_) / 128);
    embed_gemm<<<gA, dim3(256), 0, stream>>>(x, emb, Wi1, b1, X1);

    const float* X1c = X1;
    void* args[] = { (void*)&X1c, (void*)&Wh1, (void*)&Wi2, (void*)&Wh2,
                     (void*)&b2, (void*)&hb, (void*)&p1, (void*)&p2,
                     (void*)&flagsA, (void*)&flagsB };
    hipLaunchCooperativeKernel((const void*)rnn_scan, dim3(NBLK_), dim3(256),
                               args, 0, stream);

    dense_sigmoid<<<64, 64, 0, stream>>>(hb + 196608, Wd, bd, out);
}

// Round 17
// 11975.208 us; speedup vs baseline: 1.3596x; 1.1771x over previous
//
#include <hip/hip_runtime.h>

#define B_   64
#define S_   512
#define EMB_ 512
#define HID_ 1024
#define NBLK_ 256

typedef float    f32x4 __attribute__((ext_vector_type(4)));
typedef unsigned u32x4 __attribute__((ext_vector_type(4)));

// Coherent (IC/HBM-path) access: sc0 sc1 bypasses L1+L2 -> no cache-wide
// fences needed for cross-XCD exchange. Proven R5/R8/R10/R11/R14/R15.
// RULES: (R9) inline-asm loads get NO compiler-inserted s_waitcnt — every
// consumer needs an explicit vmcnt wait + sched_barrier(0). (R12) no
// runtime-indexed ext_vector arrays (scratch spills corrupt vmcnt ladders).
// (R16) per-XCD L2 mirror via hwreg XCC_ID is structurally broken — banned.
__device__ __forceinline__ f32x4 ld_coh4(const float* p) {
    f32x4 d;
    asm volatile("global_load_dwordx4 %0, %1, off sc0 sc1" : "=v"(d) : "v"(p));
    return d;
}
__device__ __forceinline__ void st_coh4(float* p, f32x4 v) {
    asm volatile("global_store_dwordx4 %0, %1, off sc0 sc1" :: "v"(p), "v"(v) : "memory");
}
__device__ __forceinline__ void st_coh1u(unsigned* p, unsigned v) {
    asm volatile("global_store_dword %0, %1, off sc0 sc1" :: "v"(p), "v"(v) : "memory");
}
// Poll load with embedded vmcnt wait — result valid at asm exit.
__device__ __forceinline__ unsigned ld_cohu_wait(const unsigned* p) {
    unsigned d;
    asm volatile("global_load_dword %0, %1, off sc0 sc1\n\t"
                 "s_waitcnt vmcnt(0)"
                 : "=v"(d) : "v"(p) : "memory");
    return d;
}

// ---------------------------------------------------------------------------
// Kernel A: X1[t][b][n] = emb[x[b][t]][:] @ Wi1[:,n] + b1[n]  (fp32; chaotic
// recurrence -> no reduced precision anywhere feeding it, R6)
// ---------------------------------------------------------------------------
__global__ __launch_bounds__(256) void embed_gemm(
    const int* __restrict__ x, const float* __restrict__ emb,
    const float* __restrict__ Wi1, const float* __restrict__ b1,
    float* __restrict__ X1)
{
    __shared__ int   tok[128];
    __shared__ float aT[32][132];
    __shared__ float bl[32][68];

    const int tid = threadIdx.x;
    const int m0  = blockIdx.y * 128;
    const int n0  = blockIdx.x * 64;

    if (tid < 128) {
        int m = m0 + tid;
        tok[tid] = x[(m & 63) * S_ + (m >> 6)];
    }
    __syncthreads();

    const int tx = tid & 15;
    const int ty = tid >> 4;

    float acc[8][4];
#pragma unroll
    for (int r = 0; r < 8; ++r)
#pragma unroll
        for (int c = 0; c < 4; ++c) acc[r][c] = 0.f;

    for (int kt = 0; kt < EMB_; kt += 32) {
#pragma unroll
        for (int j = 0; j < 4; ++j) {
            int idx = tid + j * 256;
            int r   = idx >> 3;
            int k4  = (idx & 7) * 4;
            float4 v = *(const float4*)(emb + (size_t)tok[r] * EMB_ + kt + k4);
            aT[k4 + 0][r] = v.x; aT[k4 + 1][r] = v.y;
            aT[k4 + 2][r] = v.z; aT[k4 + 3][r] = v.w;
        }
#pragma unroll
        for (int j = 0; j < 2; ++j) {
            int idx = tid + j * 256;
            int k   = idx >> 4;
            int c4  = (idx & 15) * 4;
            *(float4*)&bl[k][c4] =
                *(const float4*)(Wi1 + (size_t)(kt + k) * HID_ + n0 + c4);
        }
        __syncthreads();

#pragma unroll 4
        for (int k = 0; k < 32; ++k) {
            float4 a0 = *(const float4*)&aT[k][ty * 8];
            float4 a1 = *(const float4*)&aT[k][ty * 8 + 4];
            float4 bv = *(const float4*)&bl[k][tx * 4];
            float ar[8] = {a0.x, a0.y, a0.z, a0.w, a1.x, a1.y, a1.z, a1.w};
            float bc[4] = {bv.x, bv.y, bv.z, bv.w};
#pragma unroll
            for (int r = 0; r < 8; ++r)
#pragma unroll
                for (int c = 0; c < 4; ++c) acc[r][c] += ar[r] * bc[c];
        }
        __syncthreads();
    }

    float4 bias = *(const float4*)(b1 + n0 + tx * 4);
#pragma unroll
    for (int r = 0; r < 8; ++r) {
        int m = m0 + ty * 8 + r;
        float4 o;
        o.x = acc[r][0] + bias.x; o.y = acc[r][1] + bias.y;
        o.z = acc[r][2] + bias.z; o.w = acc[r][3] + bias.w;
        *(float4*)(X1 + (size_t)m * HID_ + n0 + tx * 4) = o;
    }
}

// shfl_xor of a whole f32x4 (per component)
__device__ __forceinline__ f32x4 shfl_xor4(f32x4 v, int m) {
    f32x4 r;
#pragma unroll
    for (int e = 0; e < 4; ++e) r[e] = __shfl_xor(v[e], m, 64);
    return r;
}

// ---------------------------------------------------------------------------
// Kernel B: persistent 3D-split scan (rows x k x cols = 2 x 8 x 16), sparse
// producer waits (R15 skeleton). Block bk: rg=bk>>7, kg=(bk>>4)&7, cg=bk&15.
// Phase A: reads h rows [32rg,+32) x k [128kg,+128) (8-lane same-address
// combining), weights 128k x 64col x3 in LDS (96 KB), computes partials for
// 32 rows x 64 cols, writes p. Phase B (role (rg, j=bk&127)): reduces 8
// kg-partials for rows [32rg,+32) x cols [8j,+8), + X1 + bias, tanh, writes h.
// Rows are independent batch chains -> the two rg halves never interact.
// Sync: W1 = flagsB[i-1][rg][16kg..+16) (h RAW) u [8cg..+8) (p WAR);
//       W2 = flagsA[i][rg][kg*16 + (j>>3)] for kg=0..8 (p RAW).
// h-write WAR covered transitively: W2 producers' W1s union = all same-rg
// flagsB[i-1] => all same-rg blocks finished step i-1 reads (R15 argument).
// ---------------------------------------------------------------------------
__global__ __launch_bounds__(256, 1) void rnn_scan(
    const float* __restrict__ X1, const float* __restrict__ Wh1,
    const float* __restrict__ Wi2, const float* __restrict__ Wh2,
    const float* __restrict__ b2, float* __restrict__ hb,
    float* __restrict__ p1, float* __restrict__ p2,
    unsigned int* __restrict__ flagsA, unsigned int* __restrict__ flagsB)
{
    __shared__ float w1s[128 * 64];   // Wh1 slice [k][c], 32 KB
    __shared__ float w2s[128 * 64];   // Wi2 slice
    __shared__ float w3s[128 * 64];   // Wh2 slice

    const int tid = threadIdx.x;
    const int bk  = blockIdx.x;
    const int rg  = bk >> 7;          // 0..1  row half
    const int kg  = (bk >> 4) & 7;    // 0..7  k-group (128 k)
    const int cg  = bk & 15;          // 0..15 col-group (64 cols)
    const int jj  = bk & 127;         // phase-B role: cols [8jj, 8jj+8)
    const int k0  = kg * 128;
    const int cs0 = cg * 64;
    const int r0  = rg * 32;

    // ---- stage weight slices (once): 128 k x 64 cols x 3 ----
    for (int idx = tid; idx < 2048; idx += 256) {
        int k = idx >> 4, c4 = (idx & 15) * 4;
        *(f32x4*)&w1s[k * 64 + c4] = *(const f32x4*)(Wh1 + (size_t)(k0 + k) * HID_ + cs0 + c4);
        *(f32x4*)&w2s[k * 64 + c4] = *(const f32x4*)(Wi2 + (size_t)(k0 + k) * HID_ + cs0 + c4);
        *(f32x4*)&w3s[k * 64 + c4] = *(const f32x4*)(Wh2 + (size_t)(k0 + k) * HID_ + cs0 + c4);
    }

    // phase-A thread mapping: (row32, c8) — owns h row r0+row32, cols 8c8..+8
    const int row32 = tid >> 3;       // 0..31
    const int c8    = tid & 7;        // 0..7
    // phase-B thread mapping: (row32b, kq8)
    const int row32b = tid >> 3;      // 0..31
    const int kq8    = tid & 7;       // 0..7

    const f32x4 b2va = *(const f32x4*)(b2 + jj * 8);
    const f32x4 b2vb = *(const f32x4*)(b2 + jj * 8 + 4);

    float* h1buf[2] = { hb, hb + 65536 };
    float* h2buf[2] = { hb + 131072, hb + 196608 };

    __syncthreads();

    for (int i = 0; i <= S_; ++i) {
        // ---- W1: sparse wait on step-(i-1) phase-B producers (same rg) ----
        if (i >= 1) {
            const unsigned* fb = flagsB + (size_t)(i - 1) * 256 + rg * 128;
            if (tid < 24) {
                int idx = (tid < 16) ? (kg * 16 + tid) : (cg * 8 + (tid - 16));
                while (ld_cohu_wait(fb + idx) == 0) __builtin_amdgcn_s_sleep(1);
            }
            __syncthreads();
        }

        // ---- phase A: h row (r0+row32), k slice [k0, k0+128) ----
        const float* h1src = h1buf[(i + 1) & 1] + (r0 + row32) * HID_ + k0;
        const float* h2src = h2buf[i & 1]       + (r0 + row32) * HID_ + k0;

        f32x4 a1lo = {0,0,0,0}, a1hi = {0,0,0,0};
        f32x4 a2lo = {0,0,0,0}, a2hi = {0,0,0,0};

        f32x4 A1[4], A2[4], B1[4], B2[4];

        // prologue: batch 0 (k 0..16) into A
#pragma unroll
        for (int r = 0; r < 4; ++r) {
            A1[r] = ld_coh4(h1src + r * 4);
            A2[r] = ld_coh4(h2src + r * 4);
        }

#pragma unroll
        for (int it = 0; it < 8; ++it) {
            if (it < 7) {
                const int kn = (it + 1) * 16;
                if (it & 1) {
#pragma unroll
                    for (int r = 0; r < 4; ++r) {
                        A1[r] = ld_coh4(h1src + kn + r * 4);
                        A2[r] = ld_coh4(h2src + kn + r * 4);
                    }
                } else {
#pragma unroll
                    for (int r = 0; r < 4; ++r) {
                        B1[r] = ld_coh4(h1src + kn + r * 4);
                        B2[r] = ld_coh4(h2src + kn + r * 4);
                    }
                }
            }
            if (it < 7) asm volatile("s_waitcnt vmcnt(8)" ::: "memory");
            else        asm volatile("s_waitcnt vmcnt(0)" ::: "memory");
            __builtin_amdgcn_sched_barrier(0);

            const f32x4* c1 = (it & 1) ? B1 : A1;
            const f32x4* c2 = (it & 1) ? B2 : A2;

#pragma unroll
            for (int q = 0; q < 4; ++q) {
#pragma unroll
                for (int e = 0; e < 4; ++e) {
                    const int kk = it * 16 + q * 4 + e;
                    const float hx = c1[q][e];
                    const float hy = c2[q][e];
                    const float* w1r = &w1s[kk * 64 + c8 * 8];
                    const float* w2r = &w2s[kk * 64 + c8 * 8];
                    const float* w3r = &w3s[kk * 64 + c8 * 8];
                    f32x4 wv1a = *(const f32x4*)(w1r);
                    f32x4 wv1b = *(const f32x4*)(w1r + 4);
                    f32x4 wv2a = *(const f32x4*)(w2r);
                    f32x4 wv2b = *(const f32x4*)(w2r + 4);
                    f32x4 wv3a = *(const f32x4*)(w3r);
                    f32x4 wv3b = *(const f32x4*)(w3r + 4);
                    a1lo += hx * wv1a;  a1hi += hx * wv1b;
                    a2lo += hx * wv2a + hy * wv3a;
                    a2hi += hx * wv2b + hy * wv3b;
                }
            }
        }

        // ---- write partials: p[kg][r0+row32][cs0 + 8c8 .. +8] ----
        {
            float* pp1 = p1 + ((size_t)kg * 64 + r0 + row32) * HID_ + cs0 + c8 * 8;
            float* pp2 = p2 + ((size_t)kg * 64 + r0 + row32) * HID_ + cs0 + c8 * 8;
            st_coh4(pp1,     a1lo); st_coh4(pp1 + 4, a1hi);
            st_coh4(pp2,     a2lo); st_coh4(pp2 + 4, a2hi);
        }

        // ---- signal p ready ----
        asm volatile("s_waitcnt vmcnt(0)" ::: "memory");
        __syncthreads();
        if (tid == 0) st_coh1u(flagsA + (size_t)i * 256 + bk, 1u);

        // ---- W2: wait my 8 kg-producers (rg, kg', cg'=jj>>3) ----
        {
            const unsigned* fa = flagsA + (size_t)i * 256 + rg * 128;
            if (tid < 8) {
                while (ld_cohu_wait(fa + tid * 16 + (jj >> 3)) == 0)
                    __builtin_amdgcn_s_sleep(1);
            }
            __syncthreads();
        }

        // ---- phase B: thread (row32b, kq8) reduces over kq8 lanes ----
        {
            const float* q1 = p1 + ((size_t)kq8 * 64 + r0 + row32b) * HID_ + jj * 8;
            const float* q2 = p2 + ((size_t)kq8 * 64 + r0 + row32b) * HID_ + jj * 8;
            f32x4 s1a = ld_coh4(q1);
            f32x4 s1b = ld_coh4(q1 + 4);
            f32x4 s2a = ld_coh4(q2);
            f32x4 s2b = ld_coh4(q2 + 4);

            f32x4 xva = {0,0,0,0}, xvb = {0,0,0,0};
            if (i < S_) {   // plain cached (X1 includes b1)
                const float* xp = X1 + ((size_t)i * B_ + r0 + row32b) * HID_ + jj * 8;
                xva = *(const f32x4*)(xp);
                xvb = *(const f32x4*)(xp + 4);
            }

            asm volatile("s_waitcnt vmcnt(0)" ::: "memory");
            __builtin_amdgcn_sched_barrier(0);

#pragma unroll
            for (int m = 1; m <= 4; m <<= 1) {
                s1a += shfl_xor4(s1a, m);
                s1b += shfl_xor4(s1b, m);
                s2a += shfl_xor4(s2a, m);
                s2b += shfl_xor4(s2b, m);
            }

            if (kq8 == 0) {
                const int row = r0 + row32b;
                if (i < S_) {
                    f32x4 oa, ob;
#pragma unroll
                    for (int e = 0; e < 4; ++e) {
                        oa[e] = tanhf(xva[e] + s1a[e]);
                        ob[e] = tanhf(xvb[e] + s1b[e]);
                    }
                    float* hp = h1buf[i & 1] + row * HID_ + jj * 8;
                    st_coh4(hp, oa); st_coh4(hp + 4, ob);
                }
                if (i >= 1) {
                    f32x4 oa, ob;
#pragma unroll
                    for (int e = 0; e < 4; ++e) {
                        oa[e] = tanhf(s2a[e] + b2va[e]);
                        ob[e] = tanhf(s2b[e] + b2vb[e]);
                    }
                    float* hp = h2buf[(i + 1) & 1] + row * HID_ + jj * 8;
                    st_coh4(hp, oa); st_coh4(hp + 4, ob);
                }
            }
        }

        // ---- signal h ready ----
        if (i < S_) {
            asm volatile("s_waitcnt vmcnt(0)" ::: "memory");
            __syncthreads();
            if (tid == 0) st_coh1u(flagsB + (size_t)i * 256 + bk, 1u);
        }
    }
    // h2(S-1) sits in h2buf[1] (= hb + 196608)
}

// ---------------------------------------------------------------------------
// out[b] = sigmoid(h2_last[b,:] @ Wd + bd)
// ---------------------------------------------------------------------------
__global__ void dense_sigmoid(const float* __restrict__ h2,
                              const float* __restrict__ Wd,
                              const float* __restrict__ bd,
                              float* __restrict__ out)
{
    int b = blockIdx.x, lane = threadIdx.x;
    float s = 0.f;
    for (int j = lane; j < HID_; j += 64) s += h2[b * HID_ + j] * Wd[j];
#pragma unroll
    for (int off = 32; off > 0; off >>= 1) s += __shfl_down(s, off, 64);
    if (lane == 0) out[b] = 1.f / (1.f + expf(-(s + bd[0])));
}

// ---------------------------------------------------------------------------
// ws layout (bytes) — identical to R15:
//   hb     @ 0          1,048,576  (4 h buffers fp32)
//   flagsA @ 1,048,576    525,312  (513 steps x 256 u32, [i][bk])
//   flagsB @ 1,573,888    524,288  (512 steps x 256 u32, [i][bk])
//   p1     @ 2,098,176  2,097,152  (8 kg x 64 rows x 1024 cols fp32)
//   p2     @ 4,195,328  2,097,152
//   X1     @ 6,292,480  134,217,728 (S*B*HID fp32)
// memset zeroes hb+flagsA+flagsB = 2,098,176 B. (p1/p2/X1 written before read.)
// ---------------------------------------------------------------------------
extern "C" void kernel_launch(void* const* d_in, const int* in_sizes, int n_in,
                              void* d_out, int out_size, void* d_ws, size_t ws_size,
                              hipStream_t stream)
{
    const int*   x   = (const int*)  d_in[0];
    const float* emb = (const float*)d_in[1];
    const float* Wi1 = (const float*)d_in[2];
    const float* Wh1 = (const float*)d_in[3];
    const float* b1  = (const float*)d_in[4];
    const float* Wi2 = (const float*)d_in[5];
    const float* Wh2 = (const float*)d_in[6];
    const float* b2  = (const float*)d_in[7];
    const float* Wd  = (const float*)d_in[8];
    const float* bd  = (const float*)d_in[9];
    float* out = (float*)d_out;

    char* w = (char*)d_ws;
    float*        hb     = (float*)w;
    unsigned int* flagsA = (unsigned int*)(w + 1048576);
    unsigned int* flagsB = (unsigned int*)(w + 1573888);
    float*        p1     = (float*)(w + 2098176);
    float*        p2     = (float*)(w + 4195328);
    float*        X1     = (float*)(w + 6292480);

    hipMemsetAsync(w, 0, 2098176, stream);

    dim3 gA(HID_ / 64, (S_ * B_) / 128);
    embed_gemm<<<gA, dim3(256), 0, stream>>>(x, emb, Wi1, b1, X1);

    const float* X1c = X1;
    void* args[] = { (void*)&X1c, (void*)&Wh1, (void*)&Wi2, (void*)&Wh2,
                     (void*)&b2, (void*)&hb, (void*)&p1, (void*)&p2,
                     (void*)&flagsA, (void*)&flagsB };
    hipLaunchCooperativeKernel((const void*)rnn_scan, dim3(NBLK_), dim3(256),
                               args, 0, stream);

    dense_sigmoid<<<64, 64, 0, stream>>>(hb + 196608, Wd, bd, out);
}